// Round 1
// baseline (680.049 us; speedup 1.0000x reference)
//
#include <hip/hip_runtime.h>
#include <math.h>

#define NNT 48
#define LL 32
#define BB 32
#define N2 (NNT*NNT)   // 2304
#define EPSV 1e-30f

__device__ __forceinline__ int ch_idx(int b, int i, int j, int n) {
    return (((b*LL + i)*(LL+1) + j)*NNT + n);
}

__global__ void clipw_kernel(const float* __restrict__ binary, float* __restrict__ W) {
    int idx = blockIdx.x*256 + threadIdx.x;
    if (idx < NNT*N2) W[idx] = fmaxf(binary[idx], EPSV);
}

__global__ void leaf_kernel(const int* __restrict__ tokens, const float* __restrict__ lexical,
                            float* __restrict__ chart, int T) {
    int idx = blockIdx.x*256 + threadIdx.x;   // over b*L*N
    if (idx >= BB*LL*NNT) return;
    int n = idx % NNT; int bi = idx / NNT; int i = bi % LL; int b = bi / LL;
    int tok = tokens[b*LL + i];
    float v = lexical[(size_t)n*(size_t)T + (size_t)tok];
    chart[ch_idx(b, i, i+1, n)] = __logf(fmaxf(v, EPSV));
}

__global__ __launch_bounds__(256) void span_kernel(const float* __restrict__ W,
                                                   float* __restrict__ chart,
                                                   int s, int pos) {
    const int inst = blockIdx.x;
    const int b = inst / pos, i = inst % pos;
    const int j = i + s, nk = s - 1;
    const int tid = threadIdx.x;
    const int lane = tid & 63;
    const int w = tid >> 6;

    __shared__ float sE[4][N2];   // per-wave partial E (36.9 KB)
    __shared__ float sAl[LL];     // alpha per split
    __shared__ float sWM[4];
    __shared__ float sS[NNT];

    // ---- pass 1: per-split alpha (max of left vec); wave-max of alpha+beta
    float wmax = -INFINITY;
    for (int kk = w; kk < nk; kk += 4) {
        int k = i + kk + 1;
        float u = (lane < NNT) ? chart[ch_idx(b, i, k, lane)] : -INFINITY;
        float v = (lane < NNT) ? chart[ch_idx(b, k, j, lane)] : -INFINITY;
        float au = u, bv = v;
        #pragma unroll
        for (int o = 32; o; o >>= 1) {
            au = fmaxf(au, __shfl_xor(au, o));
            bv = fmaxf(bv, __shfl_xor(bv, o));
        }
        if (lane == 0) sAl[kk] = au;
        wmax = fmaxf(wmax, au + bv);
    }
    if (lane == 0) sWM[w] = wmax;
    __syncthreads();
    const float M = fmaxf(fmaxf(sWM[0], sWM[1]), fmaxf(sWM[2], sWM[3]));

    // ---- pass 2: partial E in registers, e = lane + 64*t
    float E[36];
    #pragma unroll
    for (int t = 0; t < 36; ++t) E[t] = 0.f;

    for (int kk = w; kk < nk; kk += 4) {
        int k = i + kk + 1;
        float alpha = sAl[kk];
        float u = (lane < NNT) ? chart[ch_idx(b, i, k, lane)] : -INFINITY;
        float v = (lane < NNT) ? chart[ch_idx(b, k, j, lane)] : -INFINITY;
        float eu = (lane < NNT) ? __expf(u - alpha) : 0.f;       // <= 1
        float ev = (lane < NNT) ? __expf(v + alpha - M) : 0.f;   // <= 1
        // incremental decode of e -> (bb, cc), e = 48*bb + cc
        int bb = (lane >= NNT) ? 1 : 0;
        int cc = lane - NNT*bb;
        #pragma unroll
        for (int t = 0; t < 36; ++t) {
            E[t] += __shfl(eu, bb) * __shfl(ev, cc);
            cc += 16; bb += 1;
            if (cc >= NNT) { cc -= NNT; bb += 1; }
        }
    }

    // ---- write partials, combine into sE[0]
    #pragma unroll
    for (int t = 0; t < 36; ++t) sE[w][lane + (t << 6)] = E[t];
    __syncthreads();
    for (int idx = tid; idx < N2; idx += 256)
        sE[0][idx] += sE[1][idx] + sE[2][idx] + sE[3][idx];
    __syncthreads();

    // ---- step C: S[a] = sum_e E[e] * W[a][e]; wave w handles a in [12w, 12w+12)
    for (int aa = w*12; aa < w*12 + 12; ++aa) {
        const float* __restrict__ Wr = W + aa*N2;
        float acc = 0.f;
        #pragma unroll
        for (int t = 0; t < 36; ++t) {
            int e = lane + (t << 6);
            acc += sE[0][e] * Wr[e];
        }
        #pragma unroll
        for (int o = 32; o; o >>= 1) acc += __shfl_xor(acc, o);
        if (lane == 0) sS[aa] = acc;
    }
    __syncthreads();

    if (tid < NNT) chart[ch_idx(b, i, j, tid)] = M + __logf(sS[tid]);
}

__global__ void out_kernel(const float* __restrict__ chart, float* __restrict__ out) {
    int b = threadIdx.x;
    if (b < BB) out[b] = chart[ch_idx(b, 0, LL, 0)];
}

extern "C" void kernel_launch(void* const* d_in, const int* in_sizes, int n_in,
                              void* d_out, int out_size, void* d_ws, size_t ws_size,
                              hipStream_t stream) {
    const int*   tokens  = (const int*)d_in[0];
    const float* binary  = (const float*)d_in[1];
    const float* lexical = (const float*)d_in[2];
    float* out = (float*)d_out;

    float* chart = (float*)d_ws;                       // BB*LL*(LL+1)*NNT floats (6.49 MB)
    float* W     = chart + (size_t)BB*LL*(LL+1)*NNT;   // NNT*N2 floats (442 KB)

    int T = in_sizes[2] / NNT;   // 32000

    clipw_kernel<<<(NNT*N2 + 255)/256, 256, 0, stream>>>(binary, W);
    leaf_kernel<<<(BB*LL*NNT + 255)/256, 256, 0, stream>>>(tokens, lexical, chart, T);

    for (int s = 2; s <= LL; ++s) {
        int pos = LL - s + 1;
        span_kernel<<<BB*pos, 256, 0, stream>>>(W, chart, s, pos);
    }

    out_kernel<<<1, 64, 0, stream>>>(chart, out);
}

// Round 3
// 398.261 us; speedup vs baseline: 1.7075x; 1.7075x over previous
//
#include <hip/hip_runtime.h>
#include <math.h>

#define NNT 48
#define LL 32
#define BB 32
#define N2 2304            // 48*48
#define KSTEPS 72          // 2304/32
#define EPSV 1e-30f

typedef __attribute__((ext_vector_type(8))) short bf16x8;
typedef __attribute__((ext_vector_type(4))) float f32x4;

__device__ __forceinline__ int ch_idx(int b, int i, int j, int n) {
    return (((b*LL + i)*(LL+1) + j)*NNT + n);
}

__device__ __forceinline__ unsigned short f2bf(float x) {
    unsigned u = __float_as_uint(x);
    u = (u + 0x7fffu + ((u >> 16) & 1u)) >> 16;   // RNE
    return (unsigned short)u;
}

// Pack Wt[e][a] = clip(binary[a*2304+e]) into MFMA B-fragment order (bf16):
// idx = ((nt*72 + ks)*64 + lane)*8 + j ; k = ks*32 + (lane>>4)*8 + j ; n = nt*16 + (lane&15)
__global__ void wpack_kernel(const float* __restrict__ binary, unsigned short* __restrict__ Wp) {
    int idx = blockIdx.x*256 + threadIdx.x;
    if (idx >= 3*KSTEPS*64*8) return;
    int j  = idx & 7;
    int l  = (idx >> 3) & 63;
    int ks = (idx >> 9) % KSTEPS;
    int nt = idx / (KSTEPS*512);
    int k = ks*32 + ((l >> 4) << 3) + j;
    int n = nt*16 + (l & 15);
    float v = fmaxf(binary[n*N2 + k], EPSV);
    Wp[idx] = f2bf(v);
}

__global__ void leaf_kernel(const int* __restrict__ tokens, const float* __restrict__ lexical,
                            float* __restrict__ chart, int T) {
    int idx = blockIdx.x*256 + threadIdx.x;   // over b*L*N
    if (idx >= BB*LL*NNT) return;
    int n = idx % NNT; int bi = idx / NNT; int i = bi % LL; int b = bi / LL;
    int tok = tokens[b*LL + i];
    float v = lexical[(size_t)n*(size_t)T + (size_t)tok];
    chart[ch_idx(b, i, i+1, n)] = __logf(fmaxf(v, EPSV));
}

// One block = 4 instances (b,i) of span length s. 16 waves:
// wave w -> instance q=w>>2, split-subset r=w&3 (kk = r, r+4, ...).
// Phase 1: per-split alpha (left max) + per-instance global max M = max(alpha+beta).
// Phase 2: partial E[48] in regs via readlane outer-product with the two-sided
//          shift eu=exp(u-alpha)<=1, ev=exp(v+alpha-M)<=1 (both args provably <=0
//          -> overflow-free), write bf16 row w to LDS.
// Phase 3: K-split MFMA GEMM [16 rows x 2304] x [2304 x 48].
// Phase 4: reduce partials, epilogue M + log(S) -> chart.
__global__ __launch_bounds__(1024) void level_kernel(const unsigned short* __restrict__ Wp,
                                                     float* __restrict__ chart,
                                                     int s, int pos) {
    const int tid = threadIdx.x, lane = tid & 63, w = tid >> 6;
    const int q = w >> 2, r = w & 3;
    const int inst = blockIdx.x*4 + q;
    const int b = inst / pos, i = inst % pos;
    const int j = i + s, nk = s - 1;

    __shared__ __align__(16) unsigned short sEb[16][N2 + 8];  // 74.0 KB, padded rows
    __shared__ float pD[16][776];                             // 49.7 KB per-wave D partials
    __shared__ float sMp[16];
    __shared__ float sAl[16][8];                              // per-wave per-split alpha
    __shared__ float sT[16][NNT];                             // 3 KB

    // ---- phase 1: per-split alpha; wave-partial max of (alpha + beta)
    float pmax = -INFINITY;
    {
        int t = 0;
        for (int kk = r; kk < nk; kk += 4, ++t) {
            int k = i + kk + 1;
            float u = (lane < NNT) ? chart[ch_idx(b, i, k, lane)] : -INFINITY;
            float v = (lane < NNT) ? chart[ch_idx(b, k, j, lane)] : -INFINITY;
            #pragma unroll
            for (int o = 32; o; o >>= 1) {
                u = fmaxf(u, __shfl_xor(u, o));
                v = fmaxf(v, __shfl_xor(v, o));
            }
            if (lane == 0) sAl[w][t] = u;
            pmax = fmaxf(pmax, u + v);
        }
    }
    if (lane == 0) sMp[w] = pmax;
    __syncthreads();
    const float M = fmaxf(fmaxf(sMp[q*4], sMp[q*4+1]), fmaxf(sMp[q*4+2], sMp[q*4+3]));

    // ---- phase 2: partial E (lane = c, regs = b'), readlane broadcast
    float E[48];
    #pragma unroll
    for (int t = 0; t < 48; ++t) E[t] = 0.f;

    {
        int t = 0;
        for (int kk = r; kk < nk; kk += 4, ++t) {
            int k = i + kk + 1;
            float alpha = sAl[w][t];
            float u = (lane < NNT) ? chart[ch_idx(b, i, k, lane)] : -INFINITY;
            float v = (lane < NNT) ? chart[ch_idx(b, k, j, lane)] : -INFINITY;
            float eu = (lane < NNT) ? __expf(u - alpha) : 0.f;        // arg <= 0
            float ev = (lane < NNT) ? __expf(v + alpha - M) : 0.f;    // arg <= 0
            #pragma unroll
            for (int bb = 0; bb < 48; ++bb) {
                float eub = __int_as_float(__builtin_amdgcn_readlane(__float_as_int(eu), bb));
                E[bb] = fmaf(eub, ev, E[bb]);
            }
        }
    }
    if (lane < NNT) {
        #pragma unroll
        for (int bb = 0; bb < 48; ++bb) sEb[w][bb*NNT + lane] = f2bf(E[bb]);
    }
    __syncthreads();

    // ---- phase 3: MFMA GEMM, K split across 16 waves (waves 0-7: 5 ksteps, 8-15: 4)
    {
        int start = (w < 8) ? 5*w : 40 + 4*(w - 8);
        int cnt   = (w < 8) ? 5 : 4;
        f32x4 a0 = {0.f,0.f,0.f,0.f}, a1 = {0.f,0.f,0.f,0.f}, a2 = {0.f,0.f,0.f,0.f};
        const bf16x8* wp8 = (const bf16x8*)Wp;
        const int m = lane & 15, kg = lane >> 4;
        for (int t = 0; t < cnt; ++t) {
            int ks = start + t;
            bf16x8 af = *(const bf16x8*)&sEb[m][ks*32 + (kg << 3)];
            bf16x8 b0 = wp8[(0*KSTEPS + ks)*64 + lane];
            bf16x8 b1 = wp8[(1*KSTEPS + ks)*64 + lane];
            bf16x8 b2 = wp8[(2*KSTEPS + ks)*64 + lane];
            a0 = __builtin_amdgcn_mfma_f32_16x16x32_bf16(af, b0, a0, 0, 0, 0);
            a1 = __builtin_amdgcn_mfma_f32_16x16x32_bf16(af, b1, a1, 0, 0, 0);
            a2 = __builtin_amdgcn_mfma_f32_16x16x32_bf16(af, b2, a2, 0, 0, 0);
        }
        #pragma unroll
        for (int rr = 0; rr < 4; ++rr) {
            int row = (lane >> 4)*4 + rr, col = lane & 15;
            pD[w][0*256 + row*16 + col] = a0[rr];
            pD[w][1*256 + row*16 + col] = a1[rr];
            pD[w][2*256 + row*16 + col] = a2[rr];
        }
    }
    __syncthreads();

    // ---- phase 4: reduce over 16 wave-partials, then over 4 split-partial rows
    if (tid < 768) {
        int m = tid / 48, n = tid % 48, nt = n >> 4, c = n & 15;
        float sm = 0.f;
        #pragma unroll
        for (int w2 = 0; w2 < 16; ++w2) sm += pD[w2][nt*256 + m*16 + c];
        sT[m][n] = sm;
    }
    __syncthreads();
    if (tid < 192) {
        int qq = tid / 48, n = tid % 48;
        float sum = sT[4*qq][n] + sT[4*qq+1][n] + sT[4*qq+2][n] + sT[4*qq+3][n];
        float Mq = fmaxf(fmaxf(sMp[4*qq], sMp[4*qq+1]), fmaxf(sMp[4*qq+2], sMp[4*qq+3]));
        int inst2 = blockIdx.x*4 + qq;
        int b2 = inst2 / pos, i2 = inst2 % pos;
        chart[ch_idx(b2, i2, i2 + s, n)] = Mq + logf(sum);
    }
}

__global__ void out_kernel(const float* __restrict__ chart, float* __restrict__ out) {
    int b = threadIdx.x;
    if (b < BB) out[b] = chart[ch_idx(b, 0, LL, 0)];
}

extern "C" void kernel_launch(void* const* d_in, const int* in_sizes, int n_in,
                              void* d_out, int out_size, void* d_ws, size_t ws_size,
                              hipStream_t stream) {
    const int*   tokens  = (const int*)d_in[0];
    const float* binary  = (const float*)d_in[1];
    const float* lexical = (const float*)d_in[2];
    float* out = (float*)d_out;

    float* chart = (float*)d_ws;                                   // 6.49 MB
    unsigned short* Wp = (unsigned short*)(chart + (size_t)BB*LL*(LL+1)*NNT);  // 221 KB bf16

    int T = in_sizes[2] / NNT;   // 32000

    wpack_kernel<<<(3*KSTEPS*64*8 + 255)/256, 256, 0, stream>>>(binary, Wp);
    leaf_kernel<<<(BB*LL*NNT + 255)/256, 256, 0, stream>>>(tokens, lexical, chart, T);

    for (int s = 2; s <= LL; ++s) {
        int pos = LL - s + 1;
        level_kernel<<<8*pos, 1024, 0, stream>>>(Wp, chart, s, pos);
    }

    out_kernel<<<1, 64, 0, stream>>>(chart, out);
}

// Round 4
// 285.056 us; speedup vs baseline: 2.3857x; 1.3971x over previous
//
#include <hip/hip_runtime.h>
#include <math.h>

#define NNT 48
#define LL 32
#define BB 32
#define N2 2304            // 48*48
#define KSTEPS 72          // 2304/32
#define EPSV 1e-30f

typedef __attribute__((ext_vector_type(8))) short bf16x8;
typedef __attribute__((ext_vector_type(4))) float f32x4;

__device__ __forceinline__ int ch_idx(int b, int i, int j, int n) {
    return (((b*LL + i)*(LL+1) + j)*NNT + n);
}

__device__ __forceinline__ unsigned short f2bf(float x) {
    unsigned u = __float_as_uint(x);
    u = (u + 0x7fffu + ((u >> 16) & 1u)) >> 16;   // RNE
    return (unsigned short)u;
}

// Pack Wt[e][a] = clip(binary[a*2304+e]) into MFMA B-fragment order (bf16):
// idx = ((nt*72 + ks)*64 + lane)*8 + j ; k = ks*32 + (lane>>4)*8 + j ; n = nt*16 + (lane&15)
__global__ void wpack_kernel(const float* __restrict__ binary, unsigned short* __restrict__ Wp) {
    int idx = blockIdx.x*256 + threadIdx.x;
    if (idx >= 3*KSTEPS*64*8) return;
    int j  = idx & 7;
    int l  = (idx >> 3) & 63;
    int ks = (idx >> 9) % KSTEPS;
    int nt = idx / (KSTEPS*512);
    int k = ks*32 + ((l >> 4) << 3) + j;
    int n = nt*16 + (l & 15);
    float v = fmaxf(binary[n*N2 + k], EPSV);
    Wp[idx] = f2bf(v);
}

__global__ void leaf_kernel(const int* __restrict__ tokens, const float* __restrict__ lexical,
                            float* __restrict__ chart, int T) {
    int idx = blockIdx.x*256 + threadIdx.x;   // over b*L*N
    if (idx >= BB*LL*NNT) return;
    int n = idx % NNT; int bi = idx / NNT; int i = bi % LL; int b = bi / LL;
    int tok = tokens[b*LL + i];
    float v = lexical[(size_t)n*(size_t)T + (size_t)tok];
    chart[ch_idx(b, i, i+1, n)] = __logf(fmaxf(v, EPSV));
}

#define K3STEP(KS, B0, B1, B2)                                                  \
    {                                                                           \
        bf16x8 af = *(const bf16x8*)&sEb[m][(KS)*32 + (kg << 3)];               \
        a0 = __builtin_amdgcn_mfma_f32_16x16x32_bf16(af, B0, a0, 0, 0, 0);      \
        a1 = __builtin_amdgcn_mfma_f32_16x16x32_bf16(af, B1, a1, 0, 0, 0);      \
        a2 = __builtin_amdgcn_mfma_f32_16x16x32_bf16(af, B2, a2, 0, 0, 0);      \
    }

// Block = 16 waves, IPB = 16/WPI instances per block; wave w -> instance
// q = w/WPI, split subset r = w%WPI (kk = r, r+WPI, ...; <= MAXT splits).
// Phase 1: unrolled batched loads (u,v stay in regs), per-split alpha in regs,
//          per-instance M via LDS.
// Phase 2: partial E[48] via readlane outer product, eu=exp(u-a)<=1,
//          ev=exp(v+a-M)<=1 (args provably <=0 -> overflow-free), bf16 -> LDS.
// Phase 3: K-split MFMA GEMM [16 x 2304] x [2304 x 48], kstep0 prefetched
//          before the barrier.
// Phase 4: two-stage LDS reduce + epilogue M + log(S).
template<int WPI, int MAXT>
__global__ __launch_bounds__(1024) void level_kernel(const unsigned short* __restrict__ Wp,
                                                     float* __restrict__ chart,
                                                     int s, int pos) {
    constexpr int IPB = 16 / WPI;
    const int tid = threadIdx.x, lane = tid & 63, w = tid >> 6;
    const int q = w / WPI, r = w % WPI;

    // bijective XCD-aware swizzle (m204)
    int bidx;
    {
        int nwg = gridDim.x;
        int qq = nwg >> 3, rr = nwg & 7;
        int x = blockIdx.x & 7, y = blockIdx.x >> 3;
        bidx = (x < rr ? x*(qq + 1) : rr*(qq + 1) + (x - rr)*qq) + y;
    }

    const int inst = bidx*IPB + q;
    const int b = inst / pos, i = inst % pos;
    const int j = i + s, nk = s - 1;

    __shared__ __align__(16) unsigned short sEb[16][N2 + 8];  // 74.0 KB
    __shared__ float pD[16][776];                             // 49.7 KB
    __shared__ float sMp[16];
    __shared__ float sT[16][NNT];

    // ---- phase 1: batched loads, per-split alpha (regs), wave-partial max
    float u[MAXT], v[MAXT], al[MAXT];
    float pmax = -INFINITY;
    #pragma unroll
    for (int t = 0; t < MAXT; ++t) {
        int kk = r + t*WPI;
        u[t] = -INFINITY; v[t] = -INFINITY;
        if (kk < nk && lane < NNT) {
            int k = i + kk + 1;
            u[t] = chart[ch_idx(b, i, k, lane)];
            v[t] = chart[ch_idx(b, k, j, lane)];
        }
        float au = u[t], bv = v[t];
        #pragma unroll
        for (int o = 32; o; o >>= 1) {
            au = fmaxf(au, __shfl_xor(au, o));
            bv = fmaxf(bv, __shfl_xor(bv, o));
        }
        al[t] = au;
        if (kk < nk) pmax = fmaxf(pmax, au + bv);
    }
    if (lane == 0) sMp[w] = pmax;
    __syncthreads();
    float M = sMp[q*WPI];
    #pragma unroll
    for (int t = 1; t < WPI; ++t) M = fmaxf(M, sMp[q*WPI + t]);

    // ---- phase-3 kstep0 prefetch (data-independent addresses)
    const bf16x8* wp8 = (const bf16x8*)Wp;
    const int kstart = (w < 8) ? 5*w : 40 + 4*(w - 8);
    bf16x8 nb0 = wp8[(0*KSTEPS + kstart)*64 + lane];
    bf16x8 nb1 = wp8[(1*KSTEPS + kstart)*64 + lane];
    bf16x8 nb2 = wp8[(2*KSTEPS + kstart)*64 + lane];

    // ---- phase 2: partial E via readlane outer product (no reloads)
    float E[48];
    #pragma unroll
    for (int t2 = 0; t2 < 48; ++t2) E[t2] = 0.f;

    #pragma unroll
    for (int t = 0; t < MAXT; ++t) {
        int kk = r + t*WPI;
        if (kk < nk) {
            float eu = (lane < NNT) ? __expf(u[t] - al[t]) : 0.f;       // arg <= 0
            float ev = (lane < NNT) ? __expf(v[t] + al[t] - M) : 0.f;   // arg <= 0
            #pragma unroll
            for (int bb = 0; bb < 48; ++bb) {
                float eub = __int_as_float(__builtin_amdgcn_readlane(__float_as_int(eu), bb));
                E[bb] = fmaf(eub, ev, E[bb]);
            }
        }
    }
    if (lane < NNT) {
        #pragma unroll
        for (int bb = 0; bb < 48; ++bb) sEb[w][bb*NNT + lane] = f2bf(E[bb]);
    }
    __syncthreads();

    // ---- phase 3: K-split MFMA GEMM (waves 0-7: 5 ksteps, 8-15: 4)
    {
        f32x4 a0 = {0.f,0.f,0.f,0.f}, a1 = {0.f,0.f,0.f,0.f}, a2 = {0.f,0.f,0.f,0.f};
        const int m = lane & 15, kg = lane >> 4;
        if (w < 8) {
            K3STEP(kstart, nb0, nb1, nb2);
            #pragma unroll
            for (int t = 1; t < 5; ++t) {
                bf16x8 b0 = wp8[(0*KSTEPS + kstart + t)*64 + lane];
                bf16x8 b1 = wp8[(1*KSTEPS + kstart + t)*64 + lane];
                bf16x8 b2 = wp8[(2*KSTEPS + kstart + t)*64 + lane];
                K3STEP(kstart + t, b0, b1, b2);
            }
        } else {
            K3STEP(kstart, nb0, nb1, nb2);
            #pragma unroll
            for (int t = 1; t < 4; ++t) {
                bf16x8 b0 = wp8[(0*KSTEPS + kstart + t)*64 + lane];
                bf16x8 b1 = wp8[(1*KSTEPS + kstart + t)*64 + lane];
                bf16x8 b2 = wp8[(2*KSTEPS + kstart + t)*64 + lane];
                K3STEP(kstart + t, b0, b1, b2);
            }
        }
        #pragma unroll
        for (int rr = 0; rr < 4; ++rr) {
            int row = (lane >> 4)*4 + rr, col = lane & 15;
            pD[w][0*256 + row*16 + col] = a0[rr];
            pD[w][1*256 + row*16 + col] = a1[rr];
            pD[w][2*256 + row*16 + col] = a2[rr];
        }
    }
    __syncthreads();

    // ---- phase 4: reduce 16 wave-partials, then WPI split-partial rows
    if (tid < 768) {
        int m2 = tid / 48, n = tid % 48, nt = n >> 4, c = n & 15;
        float sm = 0.f;
        #pragma unroll
        for (int w2 = 0; w2 < 16; ++w2) sm += pD[w2][nt*256 + m2*16 + c];
        sT[m2][n] = sm;
    }
    __syncthreads();
    if (tid < IPB*48) {
        int qq = tid / 48, n = tid % 48;
        float sum = 0.f;
        #pragma unroll
        for (int t = 0; t < WPI; ++t) sum += sT[qq*WPI + t][n];
        float Mq = sMp[qq*WPI];
        #pragma unroll
        for (int t = 1; t < WPI; ++t) Mq = fmaxf(Mq, sMp[qq*WPI + t]);
        int inst2 = bidx*IPB + qq;
        int b2 = inst2 / pos, i2 = inst2 % pos;
        chart[ch_idx(b2, i2, i2 + s, n)] = Mq + logf(sum);
    }
}

__global__ void out_kernel(const float* __restrict__ chart, float* __restrict__ out) {
    int b = threadIdx.x;
    if (b < BB) out[b] = chart[ch_idx(b, 0, LL, 0)];
}

extern "C" void kernel_launch(void* const* d_in, const int* in_sizes, int n_in,
                              void* d_out, int out_size, void* d_ws, size_t ws_size,
                              hipStream_t stream) {
    const int*   tokens  = (const int*)d_in[0];
    const float* binary  = (const float*)d_in[1];
    const float* lexical = (const float*)d_in[2];
    float* out = (float*)d_out;

    float* chart = (float*)d_ws;                                   // 6.49 MB
    unsigned short* Wp = (unsigned short*)(chart + (size_t)BB*LL*(LL+1)*NNT);  // 221 KB bf16

    int T = in_sizes[2] / NNT;   // 32000

    wpack_kernel<<<(3*KSTEPS*64*8 + 255)/256, 256, 0, stream>>>(binary, Wp);
    leaf_kernel<<<(BB*LL*NNT + 255)/256, 256, 0, stream>>>(tokens, lexical, chart, T);

    for (int s = 2; s <= LL; ++s) {
        int pos = LL - s + 1;   // #instances per batch row = pos; total = 32*pos
        if (pos >= 17) {
            // s <= 16, nk <= 15: 4 waves/inst, <=4 splits/wave
            level_kernel<4, 4><<<8*pos, 1024, 0, stream>>>(Wp, chart, s, pos);
        } else if (pos >= 5) {
            // s = 17..28, nk <= 27: 8 waves/inst, <=4 splits/wave
            level_kernel<8, 4><<<16*pos, 1024, 0, stream>>>(Wp, chart, s, pos);
        } else {
            // s = 29..32, nk <= 31: 16 waves/inst, <=2 splits/wave
            level_kernel<16, 2><<<32*pos, 1024, 0, stream>>>(Wp, chart, s, pos);
        }
    }

    out_kernel<<<1, 64, 0, stream>>>(chart, out);
}